// Round 19
// baseline (224.313 us; speedup 1.0000x reference)
//
#include <hip/hip_runtime.h>
#include <hip/hip_bf16.h>

typedef __attribute__((ext_vector_type(8))) short short8;
typedef __attribute__((ext_vector_type(4))) float f32x4;
typedef __attribute__((ext_vector_type(2))) unsigned int uint2v;
typedef __attribute__((ext_vector_type(4))) unsigned int uint4v;

// B=64 H=W=56 C=192 WS=7 SHIFT=3 NH=6 HD=32 NW=64 L=49; 4096 windows.
static constexpr size_t OFF_QKVWT = 0;                 // 576*192*2 = 221184
static constexpr size_t OFF_PWT   = 221184;            // 192*192*2 = 73728
static constexpr size_t OFF_QB    = 294912;            // 576*4     = 2304
static constexpr size_t OFF_CMB2  = 297216;            // 24*16*64*4 f32 = 393216 B
static constexpr size_t WS_NEED   = OFF_CMB2 + 393216;

__device__ __forceinline__ ushort f2bf(float f){
  uint x = __float_as_uint(f);
  x += 0x7fffu + ((x >> 16) & 1u);
  return (ushort)(x >> 16);
}
// pack 2 f32 -> 2 bf16 (RNE) in one uint; compiler emits v_cvt_pk_bf16_f32.
__device__ __forceinline__ uint pk2(float lo, float hi){
  __hip_bfloat162 h2 = __float22bfloat162_rn(float2{lo, hi});
  uint u; __builtin_memcpy(&u, &h2, 4);
  return u;
}
__device__ __forceinline__ float exp2fast(float x){
#if __has_builtin(__builtin_amdgcn_exp2f)
  return __builtin_amdgcn_exp2f(x);
#else
  return exp2f(x);
#endif
}
__device__ __forceinline__ float rcpfast(float x){
#if __has_builtin(__builtin_amdgcn_rcpf)
  return __builtin_amdgcn_rcpf(x);
#else
  return 1.0f / x;
#endif
}
// concat two 4-bf16 groups into one 8-bf16 mfma32 fragment (slots 0..3, 4..7)
__device__ __forceinline__ short8 cat(uint2v a, uint2v b){
  uint4v u; u[0] = a[0]; u[1] = a[1]; u[2] = b[0]; u[3] = b[1];
  return __builtin_bit_cast(short8, u);
}

// ---------------------------------------------------------------- setup ----
// Weight tables in MFMA-fragment order (r14): table[T][ks][lg][lj][s],
// n = T*16+lj, k = ks*32+lg*8+s -> each wave fragment load = 1KB contiguous.
// cmb2 in r14 order: [cc][h][jg(16)][i(64)][e(4)] f32.
// log2(e) folded into q-scale and cmb so attention uses exp2 directly.
__global__ void k_setup(const float* __restrict__ qkv_w, const float* __restrict__ qkv_b,
                        const float* __restrict__ proj_w, const float* __restrict__ rel_table,
                        ushort* __restrict__ qkvwt, ushort* __restrict__ pwt,
                        float* __restrict__ qb2, float* __restrict__ cmb2){
  const float QS = 0.17677669529663687f * 1.4426950408889634f;  // HD^-0.5 * log2e
  int idx = blockIdx.x * 256 + threadIdx.x;
  if (idx < 110592){
    // qkvwt fragment layout: T(36) x ks(6) x lg(4) x lj(16) x s(8)
    int s  = idx & 7;
    int lj = (idx >> 3) & 15;
    int lg = (idx >> 7) & 3;
    int r  = idx >> 9;            // T*6 + ks
    int ks = r % 6, T = r / 6;
    int n = T*16 + lj;
    int k = ks*32 + lg*8 + s;
    float v = qkv_w[k*576 + n];
    if (n < 192) v *= QS;
    qkvwt[idx] = f2bf(v);
  } else if (idx < 110592 + 36864){
    // pwt fragment layout: T(12) x ks(6) x lg(4) x lj(16) x s(8)
    int t = idx - 110592;
    int s  = t & 7;
    int lj = (t >> 3) & 15;
    int lg = (t >> 7) & 3;
    int r  = t >> 9;
    int ks = r % 6, T = r / 6;
    int n = T*16 + lj;
    int k = ks*32 + lg*8 + s;
    pwt[t] = f2bf(proj_w[k*192 + n]);
  } else if (idx < 110592 + 36864 + 576){
    int n = idx - (110592 + 36864);
    qb2[n] = qkv_b[n] * (n < 192 ? QS : 1.0f);
  } else if (idx < 110592 + 36864 + 576 + 98304){
    int t = idx - (110592 + 36864 + 576);
    int cc = t / 24576, r = t % 24576;
    int h = r / 4096; r &= 4095;
    int jg = r >> 8, i = (r >> 2) & 63, e = r & 3;
    int j = jg*4 + e;
    float val;
    if (j >= 49) val = -1e30f;
    else if (i >= 49) val = 0.0f;
    else {
      int ii = i/7, ic = i%7, ji = j/7, jc = j%7;
      int ridx = (ii - ji + 6)*13 + (ic - jc + 6);
      float bsum = rel_table[ridx*6 + h];
      int regi = ((cc&2) ? (ii<4?1:2) : 0)*3 + ((cc&1) ? (ic<4?1:2) : 0);
      int regj = ((cc&2) ? (ji<4?1:2) : 0)*3 + ((cc&1) ? (jc<4?1:2) : 0);
      val = bsum + ((regi != regj) ? -100.0f : 0.0f);
    }
    cmb2[t] = val * 1.4426950408889634f;   // pre-scale by log2e for exp2
  }
}

// fragment address helper: ((T*6 + ks)*4 + lg)*128 + lj*8 elements
__device__ __forceinline__ const short8* wfrag(const ushort* base, int T, int ks, int lg, int lj){
  return (const short8*)(base + (((size_t)(T*6 + ks)*4 + lg) << 7) + lj*8);
}

// ---------------------------------------------------------------- fused ----
// r19 = r14 VERBATIM (201 µs bench, session best) + T5 s_setprio around the
// MFMA clusters. r15-r18 established: any layout/addressing change to this
// schedule regresses (84-reg local optimum); setprio adds only SALU hints
// (no regalloc impact). Mechanism: 12 waves (2 windows x 6 heads) are
// loosely phase-desynced, so boosting MFMA-issuing waves' priority lets
// them preempt load-issuing waves (m191: +4-7% on attn; null on lockstep).
__global__ __launch_bounds__(768, 3) void k_fused(const float* __restrict__ x,
    const ushort* __restrict__ qkvwt, const float* __restrict__ qb2,
    const ushort* __restrict__ pwt, const float* __restrict__ proj_b,
    const f32x4* __restrict__ cmb2, float* __restrict__ out){
  __shared__ ushort sbuf[2*64*200];  // per window: union xa[64][192]swz / xo[64][200]
  const int tid  = threadIdx.x;
  const int wsel = (tid >= 384) ? 1 : 0;
  const int tidl = tid - wsel*384;
  ushort* xa = sbuf + wsel*12800;
  ushort* xo = xa;
  const int wgid = blockIdx.x*2 + wsel;      // 0..4095
  const int b = wgid >> 6, win = wgid & 63;
  const int wh = win >> 3, ww = win & 7;
  const int cc = ((wh == 7) ? 2 : 0) + ((ww == 7) ? 1 : 0);

  // ---- stage x window (roll -3,-3) -> xa bf16; all loads issued first
  for (int t = tidl; t < 15*48; t += 384){
    int l = 49 + t/48, c4 = t%48;
    *(ushort4*)((char*)xa + l*384 + ((c4*8) ^ ((l&7)<<4))) = make_ushort4(0,0,0,0);
  }
  {
    float4 g[7];
    const int nit = (tidl < 48) ? 7 : 6;     // 49*48 = 2352 = 6*384 + 48
    #pragma unroll
    for (int it = 0; it < 7; it++){
      if (it < nit){
        int t = tidl + it*384;
        int l = t/48, c4 = t%48;
        int i = l/7, j = l%7;
        int sh = wh*7 + i + 3; if (sh >= 56) sh -= 56;
        int sw = ww*7 + j + 3; if (sw >= 56) sw -= 56;
        g[it] = *(const float4*)(x + (((size_t)b*56 + sh)*56 + sw)*192 + c4*4);
      }
    }
    #pragma unroll
    for (int it = 0; it < 7; it++){
      if (it < nit){
        int t = tidl + it*384;
        int l = t/48, c4 = t%48;
        uint2v u = { pk2(g[it].x, g[it].y), pk2(g[it].z, g[it].w) };
        *(uint2v*)((char*)xa + l*384 + ((c4*8) ^ ((l&7)<<4))) = u;
      }
    }
  }
  __syncthreads();

  const int h = tidl >> 6, lane = tidl & 63, lj = lane & 15, lg = lane >> 4;
  const int swz = (lj & 7) << 4;

  uint2v q16[2][4], k16[2][4], v16[2][4];  // [d-slice dt][l/j tile]; 4 bf16/lane

  { // ---- q,k via swapped GEMM: D[c_out][l], lane: col=l=lj, d in regs
    f32x4 acc[4][4];
    #pragma unroll
    for (int mt = 0; mt < 4; mt++)
      #pragma unroll
      for (int nt = 0; nt < 4; nt++) acc[mt][nt] = (f32x4){0.f,0.f,0.f,0.f};
    #pragma unroll
    for (int ks = 0; ks < 6; ks++){
      short8 xb[4];
      #pragma unroll
      for (int nt = 0; nt < 4; nt++)
        xb[nt] = *(const short8*)((const char*)xa + (nt*16+lj)*384 + ((ks*64 + lg*16) ^ swz));
      #pragma unroll
      for (int mt = 0; mt < 4; mt++){
        int T = (mt>>1)*12 + h*2 + (mt&1);     // tile of row (mt>>1)*192+h*32+(mt&1)*16
        short8 wa = *wfrag(qkvwt, T, ks, lg, lj);
        __builtin_amdgcn_s_setprio(1);
        #pragma unroll
        for (int nt = 0; nt < 4; nt++)
          acc[mt][nt] = __builtin_amdgcn_mfma_f32_16x16x32_bf16(wa, xb[nt], acc[mt][nt], 0, 0, 0);
        __builtin_amdgcn_s_setprio(0);
      }
    }
    #pragma unroll
    for (int mt = 0; mt < 4; mt++){
      int cb = (mt>>1)*192 + h*32 + (mt&1)*16 + lg*4;
      float b0 = qb2[cb], b1 = qb2[cb+1], b2 = qb2[cb+2], b3 = qb2[cb+3];
      #pragma unroll
      for (int nt = 0; nt < 4; nt++){
        f32x4 a = acc[mt][nt];
        uint2v pk = { pk2(a[0]+b0, a[1]+b1), pk2(a[2]+b2, a[3]+b3) };
        if (mt < 2) q16[mt][nt] = pk; else k16[mt-2][nt] = pk;
      }
    }
  }
  { // ---- v via normal GEMM: D[l][c_out], lane: col=d=lj, j in regs
    f32x4 acc[4][2];
    #pragma unroll
    for (int mt = 0; mt < 4; mt++){ acc[mt][0] = (f32x4){0.f,0.f,0.f,0.f}; acc[mt][1] = (f32x4){0.f,0.f,0.f,0.f}; }
    #pragma unroll
    for (int ks = 0; ks < 6; ks++){
      short8 xf[4];
      #pragma unroll
      for (int mt = 0; mt < 4; mt++)
        xf[mt] = *(const short8*)((const char*)xa + (mt*16+lj)*384 + ((ks*64 + lg*16) ^ swz));
      #pragma unroll
      for (int nt = 0; nt < 2; nt++){
        short8 wb = *wfrag(qkvwt, 24 + h*2 + nt, ks, lg, lj);
        __builtin_amdgcn_s_setprio(1);
        #pragma unroll
        for (int mt = 0; mt < 4; mt++)
          acc[mt][nt] = __builtin_amdgcn_mfma_f32_16x16x32_bf16(xf[mt], wb, acc[mt][nt], 0, 0, 0);
        __builtin_amdgcn_s_setprio(0);
      }
    }
    float vb0 = qb2[384 + h*32 + lj], vb1 = qb2[384 + h*32 + 16 + lj];
    #pragma unroll
    for (int mt = 0; mt < 4; mt++){
      f32x4 a0 = acc[mt][0], a1 = acc[mt][1];
      v16[0][mt] = (uint2v){ pk2(a0[0]+vb0, a0[1]+vb0), pk2(a0[2]+vb0, a0[3]+vb0) };
      v16[1][mt] = (uint2v){ pk2(a1[0]+vb1, a1[1]+vb1), pk2(a1[2]+vb1, a1[3]+vb1) };
    }
  }
  float sInv[4];
  uint2v p16[4][4];
  { // ---- attention: S^T = K·Q^T + cmb' (C-op), p = exp2(S'), defer 1/s
    const f32x4* cb = cmb2 + (size_t)(cc*6 + h)*16*64;
    f32x4 st[4][4];  // [jt][it]: lane col=i=it*16+lj, regs j=jt*16+lg*4+e
    #pragma unroll
    for (int jt = 0; jt < 4; jt++)
      #pragma unroll
      for (int it = 0; it < 4; it++)
        st[jt][it] = cb[(jt*4 + lg)*64 + it*16 + lj];
    __builtin_amdgcn_s_setprio(1);
    #pragma unroll
    for (int jt = 0; jt < 4; jt++)
      #pragma unroll
      for (int it = 0; it < 4; it++)
        st[jt][it] = __builtin_amdgcn_mfma_f32_16x16x32_bf16(
            cat(k16[0][jt], k16[1][jt]), cat(q16[0][it], q16[1][it]), st[jt][it], 0, 0, 0);
    __builtin_amdgcn_s_setprio(0);

    #pragma unroll
    for (int it = 0; it < 4; it++){
      float s = 0.f;
      #pragma unroll
      for (int jt = 0; jt < 4; jt++)
        #pragma unroll
        for (int e = 0; e < 4; e++){
          float p = exp2fast(st[jt][it][e]);
          st[jt][it][e] = p; s += p;
        }
      s += __shfl_xor(s, 16); s += __shfl_xor(s, 32);
      sInv[it] = rcpfast(s);
      #pragma unroll
      for (int jt = 0; jt < 4; jt++)
        p16[jt][it] = (uint2v){ pk2(st[jt][it][0], st[jt][it][1]),
                                pk2(st[jt][it][2], st[jt][it][3]) };
    }
  }

  // xa is dead from here on; reuse the buffer as xo. The barrier is also a
  // live-range fence for the 84-reg schedule (r9/r15/r17 lesson) — keep it.
  __syncthreads();

  { // ---- PV: O^T = V^T . P^T, normalize by sInv at epilogue, write xo
    #pragma unroll
    for (int dt = 0; dt < 2; dt++)
      #pragma unroll
      for (int it = 0; it < 4; it++){
        __builtin_amdgcn_s_setprio(1);
        f32x4 o = __builtin_amdgcn_mfma_f32_16x16x32_bf16(
            cat(v16[dt][0], v16[dt][1]), cat(p16[0][it], p16[1][it]),
            (f32x4){0.f,0.f,0.f,0.f}, 0, 0, 0);
        o = __builtin_amdgcn_mfma_f32_16x16x32_bf16(
            cat(v16[dt][2], v16[dt][3]), cat(p16[2][it], p16[3][it]), o, 0, 0, 0);
        __builtin_amdgcn_s_setprio(0);
        float inv = sInv[it];
        uint2v w = { pk2(o[0]*inv, o[1]*inv), pk2(o[2]*inv, o[3]*inv) };
        *(uint2v*)((char*)xo + (it*16+lj)*400 + (h*32 + dt*16 + lg*4)*2) = w;
      }
  }
  __syncthreads();
  { // ---- proj: D[l][c_out] = xo @ proj_w, scatter with roll(+3,+3)
    f32x4 acc[4][2];
    #pragma unroll
    for (int mt = 0; mt < 4; mt++){ acc[mt][0] = (f32x4){0.f,0.f,0.f,0.f}; acc[mt][1] = (f32x4){0.f,0.f,0.f,0.f}; }
    #pragma unroll
    for (int ks = 0; ks < 6; ks++){
      short8 xf[4];
      #pragma unroll
      for (int mt = 0; mt < 4; mt++)
        xf[mt] = *(const short8*)((const char*)xo + (mt*16+lj)*400 + ks*64 + lg*16);
      #pragma unroll
      for (int nt = 0; nt < 2; nt++){
        short8 pw = *wfrag(pwt, h*2 + nt, ks, lg, lj);
        __builtin_amdgcn_s_setprio(1);
        #pragma unroll
        for (int mt = 0; mt < 4; mt++)
          acc[mt][nt] = __builtin_amdgcn_mfma_f32_16x16x32_bf16(xf[mt], pw, acc[mt][nt], 0, 0, 0);
        __builtin_amdgcn_s_setprio(0);
      }
    }
    float pb0 = proj_b[h*32 + lj], pb1 = proj_b[h*32 + 16 + lj];
    #pragma unroll
    for (int mt = 0; mt < 4; mt++)
      #pragma unroll
      for (int e = 0; e < 4; e++){
        int l = mt*16 + lg*4 + e;
        if (l < 49){
          int i = l/7, jx = l%7;
          int oh = wh*7 + i + 3; if (oh >= 56) oh -= 56;
          int ow = ww*7 + jx + 3; if (ow >= 56) ow -= 56;
          size_t base = (((size_t)b*56 + oh)*56 + ow)*192 + h*32;
          out[base + lj]      = acc[mt][0][e] + pb0;
          out[base + 16 + lj] = acc[mt][1][e] + pb1;
        }
      }
  }
}

// ------------------------------------------------------------------ launch -
extern "C" void kernel_launch(void* const* d_in, const int* in_sizes, int n_in,
                              void* d_out, int out_size, void* d_ws, size_t ws_size,
                              hipStream_t stream){
  const float* x         = (const float*)d_in[0];
  const float* qkv_w     = (const float*)d_in[1];
  const float* qkv_b     = (const float*)d_in[2];
  const float* proj_w    = (const float*)d_in[3];
  const float* proj_b    = (const float*)d_in[4];
  const float* rel_table = (const float*)d_in[5];

  if (ws_size < WS_NEED) return;

  char* ws = (char*)d_ws;
  ushort* qkvwt = (ushort*)(ws + OFF_QKVWT);
  ushort* pwt   = (ushort*)(ws + OFF_PWT);
  float*  qb2   = (float*) (ws + OFF_QB);
  float*  cmb2  = (float*) (ws + OFF_CMB2);
  float* out = (float*)d_out;

  k_setup<<<dim3(963), dim3(256), 0, stream>>>(qkv_w, qkv_b, proj_w, rel_table, qkvwt, pwt, qb2, cmb2);
  k_fused<<<dim3(2048), dim3(768), 0, stream>>>(x, qkvwt, qb2, pwt, proj_b, (const f32x4*)cmb2, out);
}

// Round 20
// 200.135 us; speedup vs baseline: 1.1208x; 1.1208x over previous
//
#include <hip/hip_runtime.h>
#include <hip/hip_bf16.h>

typedef __attribute__((ext_vector_type(8))) short short8;
typedef __attribute__((ext_vector_type(4))) float f32x4;
typedef __attribute__((ext_vector_type(2))) unsigned int uint2v;
typedef __attribute__((ext_vector_type(4))) unsigned int uint4v;

// B=64 H=W=56 C=192 WS=7 SHIFT=3 NH=6 HD=32 NW=64 L=49; 4096 windows.
static constexpr size_t OFF_QKVWT = 0;                 // 576*192*2 = 221184
static constexpr size_t OFF_PWT   = 221184;            // 192*192*2 = 73728
static constexpr size_t OFF_QB    = 294912;            // 576*4     = 2304
static constexpr size_t OFF_CMB2  = 297216;            // 24*16*64*4 f32 = 393216 B
static constexpr size_t WS_NEED   = OFF_CMB2 + 393216;

__device__ __forceinline__ ushort f2bf(float f){
  uint x = __float_as_uint(f);
  x += 0x7fffu + ((x >> 16) & 1u);
  return (ushort)(x >> 16);
}
// pack 2 f32 -> 2 bf16 (RNE) in one uint; compiler emits v_cvt_pk_bf16_f32.
__device__ __forceinline__ uint pk2(float lo, float hi){
  __hip_bfloat162 h2 = __float22bfloat162_rn(float2{lo, hi});
  uint u; __builtin_memcpy(&u, &h2, 4);
  return u;
}
__device__ __forceinline__ float exp2fast(float x){
#if __has_builtin(__builtin_amdgcn_exp2f)
  return __builtin_amdgcn_exp2f(x);
#else
  return exp2f(x);
#endif
}
__device__ __forceinline__ float rcpfast(float x){
#if __has_builtin(__builtin_amdgcn_rcpf)
  return __builtin_amdgcn_rcpf(x);
#else
  return 1.0f / x;
#endif
}
// concat two 4-bf16 groups into one 8-bf16 mfma32 fragment (slots 0..3, 4..7)
__device__ __forceinline__ short8 cat(uint2v a, uint2v b){
  uint4v u; u[0] = a[0]; u[1] = a[1]; u[2] = b[0]; u[3] = b[1];
  return __builtin_bit_cast(short8, u);
}

// ---------------------------------------------------------------- setup ----
// Weight tables stored in MFMA-FRAGMENT ORDER (r14):
//   table[T][ks][lg][lj][s]  with  n = T*16+lj, k = ks*32+lg*8+s.
// A wave's fragment load (fixed T,ks) is ONE contiguous 1KB block (fully
// coalesced), and ks-sequential loads are adjacent (L1-friendly). This was
// the single biggest win of the session (270->228 profile, 243->201 bench).
// log2(e) folded into q-scale and cmb so attention uses exp2 directly.
__global__ void k_setup(const float* __restrict__ qkv_w, const float* __restrict__ qkv_b,
                        const float* __restrict__ proj_w, const float* __restrict__ rel_table,
                        ushort* __restrict__ qkvwt, ushort* __restrict__ pwt,
                        float* __restrict__ qb2, float* __restrict__ cmb2){
  const float QS = 0.17677669529663687f * 1.4426950408889634f;  // HD^-0.5 * log2e
  int idx = blockIdx.x * 256 + threadIdx.x;
  if (idx < 110592){
    // qkvwt fragment layout: T(36) x ks(6) x lg(4) x lj(16) x s(8)
    int s  = idx & 7;
    int lj = (idx >> 3) & 15;
    int lg = (idx >> 7) & 3;
    int r  = idx >> 9;            // T*6 + ks
    int ks = r % 6, T = r / 6;
    int n = T*16 + lj;
    int k = ks*32 + lg*8 + s;
    float v = qkv_w[k*576 + n];
    if (n < 192) v *= QS;
    qkvwt[idx] = f2bf(v);
  } else if (idx < 110592 + 36864){
    // pwt fragment layout: T(12) x ks(6) x lg(4) x lj(16) x s(8)
    int t = idx - 110592;
    int s  = t & 7;
    int lj = (t >> 3) & 15;
    int lg = (t >> 7) & 3;
    int r  = t >> 9;
    int ks = r % 6, T = r / 6;
    int n = T*16 + lj;
    int k = ks*32 + lg*8 + s;
    pwt[t] = f2bf(proj_w[k*192 + n]);
  } else if (idx < 110592 + 36864 + 576){
    int n = idx - (110592 + 36864);
    qb2[n] = qkv_b[n] * (n < 192 ? QS : 1.0f);
  } else if (idx < 110592 + 36864 + 576 + 98304){
    int t = idx - (110592 + 36864 + 576);
    int cc = t / 24576, r = t % 24576;
    int h = r / 4096; r &= 4095;
    int jg = r >> 8, i = (r >> 2) & 63, e = r & 3;
    int j = jg*4 + e;
    float val;
    if (j >= 49) val = -1e30f;
    else if (i >= 49) val = 0.0f;
    else {
      int ii = i/7, ic = i%7, ji = j/7, jc = j%7;
      int ridx = (ii - ji + 6)*13 + (ic - jc + 6);
      float bsum = rel_table[ridx*6 + h];
      int regi = ((cc&2) ? (ii<4?1:2) : 0)*3 + ((cc&1) ? (ic<4?1:2) : 0);
      int regj = ((cc&2) ? (ji<4?1:2) : 0)*3 + ((cc&1) ? (jc<4?1:2) : 0);
      val = bsum + ((regi != regj) ? -100.0f : 0.0f);
    }
    cmb2[t] = val * 1.4426950408889634f;   // pre-scale by log2e for exp2
  }
}

// fragment address helper: ((T*6 + ks)*4 + lg)*128 + lj*8 elements
__device__ __forceinline__ const short8* wfrag(const ushort* base, int T, int ks, int lg, int lj){
  return (const short8*)(base + (((size_t)(T*6 + ks)*4 + lg) << 7) + lj*8);
}

// ---------------------------------------------------------------- fused ----
// FINAL (r20 = r14, session best: 201 µs bench / 228 µs profile).
// One block = TWO windows x 6 heads = 12 waves; each wave owns one
// (window, head); q/k/v/P never leave registers (swapped-GEMM layout trick
// keeps every MFMA chain slot-consistent with K=32 bf16 MFMAs only).
// Session ladder: 550 (r1 split kernels) -> 342 (fused) -> 263 (exp2
// softmax, no-max, deferred 1/s, issue-early staging) -> 254 (hw cvt_pk)
// -> 243 (12-wave blocks) -> 201 (fragment-ordered weights).
// Exhausted-and-reverted: LDS union growth (r4 spill), 2-win/wave ILP (r7
// spill), merged qkv GEMM (r13 spill), xo swizzle (r9/r15/r17: conflicts
// -4x but schedule perturbation costs more), waves_per_eu (r16 no-op),
// coalesced cmb (r18 -4%), setprio (r19 -11%: barrier-lockstep regime).
// The 84-VGPR schedule is a local optimum; every addressing/hint
// perturbation measured worse. Not a HW roofline (MfmaUtil 16%) — further
// gains need a ground-up redesign (<=64-VGPR waves for 2-block residency
// or producer/consumer specialization), not increments on this structure.
__global__ __launch_bounds__(768, 3) void k_fused(const float* __restrict__ x,
    const ushort* __restrict__ qkvwt, const float* __restrict__ qb2,
    const ushort* __restrict__ pwt, const float* __restrict__ proj_b,
    const f32x4* __restrict__ cmb2, float* __restrict__ out){
  __shared__ ushort sbuf[2*64*200];  // per window: union xa[64][192]swz / xo[64][200]
  const int tid  = threadIdx.x;
  const int wsel = (tid >= 384) ? 1 : 0;
  const int tidl = tid - wsel*384;
  ushort* xa = sbuf + wsel*12800;
  ushort* xo = xa;
  const int wgid = blockIdx.x*2 + wsel;      // 0..4095
  const int b = wgid >> 6, win = wgid & 63;
  const int wh = win >> 3, ww = win & 7;
  const int cc = ((wh == 7) ? 2 : 0) + ((ww == 7) ? 1 : 0);

  // ---- stage x window (roll -3,-3) -> xa bf16; all loads issued first
  for (int t = tidl; t < 15*48; t += 384){
    int l = 49 + t/48, c4 = t%48;
    *(ushort4*)((char*)xa + l*384 + ((c4*8) ^ ((l&7)<<4))) = make_ushort4(0,0,0,0);
  }
  {
    float4 g[7];
    const int nit = (tidl < 48) ? 7 : 6;     // 49*48 = 2352 = 6*384 + 48
    #pragma unroll
    for (int it = 0; it < 7; it++){
      if (it < nit){
        int t = tidl + it*384;
        int l = t/48, c4 = t%48;
        int i = l/7, j = l%7;
        int sh = wh*7 + i + 3; if (sh >= 56) sh -= 56;
        int sw = ww*7 + j + 3; if (sw >= 56) sw -= 56;
        g[it] = *(const float4*)(x + (((size_t)b*56 + sh)*56 + sw)*192 + c4*4);
      }
    }
    #pragma unroll
    for (int it = 0; it < 7; it++){
      if (it < nit){
        int t = tidl + it*384;
        int l = t/48, c4 = t%48;
        uint2v u = { pk2(g[it].x, g[it].y), pk2(g[it].z, g[it].w) };
        *(uint2v*)((char*)xa + l*384 + ((c4*8) ^ ((l&7)<<4))) = u;
      }
    }
  }
  __syncthreads();

  const int h = tidl >> 6, lane = tidl & 63, lj = lane & 15, lg = lane >> 4;
  const int swz = (lj & 7) << 4;

  uint2v q16[2][4], k16[2][4], v16[2][4];  // [d-slice dt][l/j tile]; 4 bf16/lane

  { // ---- q,k via swapped GEMM: D[c_out][l], lane: col=l=lj, d in regs
    f32x4 acc[4][4];
    #pragma unroll
    for (int mt = 0; mt < 4; mt++)
      #pragma unroll
      for (int nt = 0; nt < 4; nt++) acc[mt][nt] = (f32x4){0.f,0.f,0.f,0.f};
    #pragma unroll
    for (int ks = 0; ks < 6; ks++){
      short8 xb[4];
      #pragma unroll
      for (int nt = 0; nt < 4; nt++)
        xb[nt] = *(const short8*)((const char*)xa + (nt*16+lj)*384 + ((ks*64 + lg*16) ^ swz));
      #pragma unroll
      for (int mt = 0; mt < 4; mt++){
        int T = (mt>>1)*12 + h*2 + (mt&1);     // tile of row (mt>>1)*192+h*32+(mt&1)*16
        short8 wa = *wfrag(qkvwt, T, ks, lg, lj);
        #pragma unroll
        for (int nt = 0; nt < 4; nt++)
          acc[mt][nt] = __builtin_amdgcn_mfma_f32_16x16x32_bf16(wa, xb[nt], acc[mt][nt], 0, 0, 0);
      }
    }
    #pragma unroll
    for (int mt = 0; mt < 4; mt++){
      int cb = (mt>>1)*192 + h*32 + (mt&1)*16 + lg*4;
      float b0 = qb2[cb], b1 = qb2[cb+1], b2 = qb2[cb+2], b3 = qb2[cb+3];
      #pragma unroll
      for (int nt = 0; nt < 4; nt++){
        f32x4 a = acc[mt][nt];
        uint2v pk = { pk2(a[0]+b0, a[1]+b1), pk2(a[2]+b2, a[3]+b3) };
        if (mt < 2) q16[mt][nt] = pk; else k16[mt-2][nt] = pk;
      }
    }
  }
  { // ---- v via normal GEMM: D[l][c_out], lane: col=d=lj, j in regs
    f32x4 acc[4][2];
    #pragma unroll
    for (int mt = 0; mt < 4; mt++){ acc[mt][0] = (f32x4){0.f,0.f,0.f,0.f}; acc[mt][1] = (f32x4){0.f,0.f,0.f,0.f}; }
    #pragma unroll
    for (int ks = 0; ks < 6; ks++){
      short8 xf[4];
      #pragma unroll
      for (int mt = 0; mt < 4; mt++)
        xf[mt] = *(const short8*)((const char*)xa + (mt*16+lj)*384 + ((ks*64 + lg*16) ^ swz));
      #pragma unroll
      for (int nt = 0; nt < 2; nt++){
        short8 wb = *wfrag(qkvwt, 24 + h*2 + nt, ks, lg, lj);
        #pragma unroll
        for (int mt = 0; mt < 4; mt++)
          acc[mt][nt] = __builtin_amdgcn_mfma_f32_16x16x32_bf16(xf[mt], wb, acc[mt][nt], 0, 0, 0);
      }
    }
    float vb0 = qb2[384 + h*32 + lj], vb1 = qb2[384 + h*32 + 16 + lj];
    #pragma unroll
    for (int mt = 0; mt < 4; mt++){
      f32x4 a0 = acc[mt][0], a1 = acc[mt][1];
      v16[0][mt] = (uint2v){ pk2(a0[0]+vb0, a0[1]+vb0), pk2(a0[2]+vb0, a0[3]+vb0) };
      v16[1][mt] = (uint2v){ pk2(a1[0]+vb1, a1[1]+vb1), pk2(a1[2]+vb1, a1[3]+vb1) };
    }
  }
  float sInv[4];
  uint2v p16[4][4];
  { // ---- attention: S^T = K·Q^T + cmb' (C-op), p = exp2(S'), defer 1/s
    const f32x4* cb = cmb2 + (size_t)(cc*6 + h)*16*64;
    f32x4 st[4][4];  // [jt][it]: lane col=i=it*16+lj, regs j=jt*16+lg*4+e
    #pragma unroll
    for (int jt = 0; jt < 4; jt++)
      #pragma unroll
      for (int it = 0; it < 4; it++)
        st[jt][it] = cb[(jt*4 + lg)*64 + it*16 + lj];
    #pragma unroll
    for (int jt = 0; jt < 4; jt++)
      #pragma unroll
      for (int it = 0; it < 4; it++)
        st[jt][it] = __builtin_amdgcn_mfma_f32_16x16x32_bf16(
            cat(k16[0][jt], k16[1][jt]), cat(q16[0][it], q16[1][it]), st[jt][it], 0, 0, 0);

    #pragma unroll
    for (int it = 0; it < 4; it++){
      float s = 0.f;
      #pragma unroll
      for (int jt = 0; jt < 4; jt++)
        #pragma unroll
        for (int e = 0; e < 4; e++){
          float p = exp2fast(st[jt][it][e]);
          st[jt][it][e] = p; s += p;
        }
      s += __shfl_xor(s, 16); s += __shfl_xor(s, 32);
      sInv[it] = rcpfast(s);
      #pragma unroll
      for (int jt = 0; jt < 4; jt++)
        p16[jt][it] = (uint2v){ pk2(st[jt][it][0], st[jt][it][1]),
                                pk2(st[jt][it][2], st[jt][it][3]) };
    }
  }

  // xa is dead from here on; reuse the buffer as xo. The barrier is also a
  // live-range fence for the 84-reg schedule (r9/r15/r17 lesson) — keep it.
  __syncthreads();

  { // ---- PV: O^T = V^T . P^T, normalize by sInv at epilogue, write xo
    #pragma unroll
    for (int dt = 0; dt < 2; dt++)
      #pragma unroll
      for (int it = 0; it < 4; it++){
        f32x4 o = __builtin_amdgcn_mfma_f32_16x16x32_bf16(
            cat(v16[dt][0], v16[dt][1]), cat(p16[0][it], p16[1][it]),
            (f32x4){0.f,0.f,0.f,0.f}, 0, 0, 0);
        o = __builtin_amdgcn_mfma_f32_16x16x32_bf16(
            cat(v16[dt][2], v16[dt][3]), cat(p16[2][it], p16[3][it]), o, 0, 0, 0);
        float inv = sInv[it];
        uint2v w = { pk2(o[0]*inv, o[1]*inv), pk2(o[2]*inv, o[3]*inv) };
        *(uint2v*)((char*)xo + (it*16+lj)*400 + (h*32 + dt*16 + lg*4)*2) = w;
      }
  }
  __syncthreads();
  { // ---- proj: D[l][c_out] = xo @ proj_w, scatter with roll(+3,+3)
    f32x4 acc[4][2];
    #pragma unroll
    for (int mt = 0; mt < 4; mt++){ acc[mt][0] = (f32x4){0.f,0.f,0.f,0.f}; acc[mt][1] = (f32x4){0.f,0.f,0.f,0.f}; }
    #pragma unroll
    for (int ks = 0; ks < 6; ks++){
      short8 xf[4];
      #pragma unroll
      for (int mt = 0; mt < 4; mt++)
        xf[mt] = *(const short8*)((const char*)xo + (mt*16+lj)*400 + ks*64 + lg*16);
      #pragma unroll
      for (int nt = 0; nt < 2; nt++){
        short8 pw = *wfrag(pwt, h*2 + nt, ks, lg, lj);
        #pragma unroll
        for (int mt = 0; mt < 4; mt++)
          acc[mt][nt] = __builtin_amdgcn_mfma_f32_16x16x32_bf16(xf[mt], pw, acc[mt][nt], 0, 0, 0);
      }
    }
    float pb0 = proj_b[h*32 + lj], pb1 = proj_b[h*32 + 16 + lj];
    #pragma unroll
    for (int mt = 0; mt < 4; mt++)
      #pragma unroll
      for (int e = 0; e < 4; e++){
        int l = mt*16 + lg*4 + e;
        if (l < 49){
          int i = l/7, jx = l%7;
          int oh = wh*7 + i + 3; if (oh >= 56) oh -= 56;
          int ow = ww*7 + jx + 3; if (ow >= 56) ow -= 56;
          size_t base = (((size_t)b*56 + oh)*56 + ow)*192 + h*32;
          out[base + lj]      = acc[mt][0][e] + pb0;
          out[base + 16 + lj] = acc[mt][1][e] + pb1;
        }
      }
  }
}

// ------------------------------------------------------------------ launch -
extern "C" void kernel_launch(void* const* d_in, const int* in_sizes, int n_in,
                              void* d_out, int out_size, void* d_ws, size_t ws_size,
                              hipStream_t stream){
  const float* x         = (const float*)d_in[0];
  const float* qkv_w     = (const float*)d_in[1];
  const float* qkv_b     = (const float*)d_in[2];
  const float* proj_w    = (const float*)d_in[3];
  const float* proj_b    = (const float*)d_in[4];
  const float* rel_table = (const float*)d_in[5];

  if (ws_size < WS_NEED) return;

  char* ws = (char*)d_ws;
  ushort* qkvwt = (ushort*)(ws + OFF_QKVWT);
  ushort* pwt   = (ushort*)(ws + OFF_PWT);
  float*  qb2   = (float*) (ws + OFF_QB);
  float*  cmb2  = (float*) (ws + OFF_CMB2);
  float* out = (float*)d_out;

  k_setup<<<dim3(963), dim3(256), 0, stream>>>(qkv_w, qkv_b, proj_w, rel_table, qkvwt, pwt, qb2, cmb2);
  k_fused<<<dim3(2048), dim3(768), 0, stream>>>(x, qkvwt, qb2, pwt, proj_b, (const f32x4*)cmb2, out);
}